// Round 6
// baseline (5037.038 us; speedup 1.0000x reference)
//
#include <hip/hip_runtime.h>
#include <hip/hip_bf16.h>
#include <math.h>

#define NODE 90
#define HID 256
#define NB 512
#define NN (NB * NODE)
#define EDGES (NB * 2700)

typedef __hip_bfloat16 bf16;

__device__ __forceinline__ float scrub(float v) { return isfinite(v) ? v : 0.f; }

__device__ __forceinline__ float tanh_safe(float s) {
    s = fminf(fmaxf(s, -15.f), 15.f);
    float t = __expf(2.f * s);
    return (t - 1.f) / (t + 1.f);
}

// ---------------------------------------------------------------------------
// Module-scope fp32 scratch (~286 MB .bss). d_ws unused.
// ---------------------------------------------------------------------------
__device__ float g_adjS[(size_t)NB * NODE * NODE];
__device__ float g_adjF[(size_t)NB * NODE * NODE];
__device__ float g_A[(size_t)NB * NODE * NODE];
__device__ float g_T[(size_t)NN * HID];
__device__ float g_hs[(size_t)NN * HID];
__device__ float g_hf[(size_t)NN * HID];
__device__ float g_cs[(size_t)NN * HID];
__device__ float g_cf[(size_t)NN * HID];
__device__ int g_flags[2];   // [0]: 0=x fp32, 1=x bf16   [1]: 0=edges int32, 1=edges int64

__device__ __forceinline__ float* adjPtr(int w) { return w ? g_adjF : g_adjS; }
__device__ __forceinline__ float* selbuf(int w) {
    switch (w) {
        case 0: return g_hs;
        case 1: return g_hf;
        case 2: return g_cs;
        default: return g_cf;
    }
}

// flagged float read: interprets p as fp32 (flag=0) or bf16 (flag=1)
__device__ __forceinline__ float ldf(const void* p, size_t i, int flag) {
    if (flag) return scrub(__bfloat162float(((const bf16*)p)[i]));
    return scrub(((const float*)p)[i]);
}

// ---------------------------------------------------------------------------
// Detect input dtypes once (deterministic; same result every launch).
// ---------------------------------------------------------------------------
__global__ void k_detect(const void* x, const void* edges) {
    if (threadIdx.x != 0 || blockIdx.x != 0) return;
    const float* xf = (const float*)x;
    float mx = 0.f;
    for (int i = 0; i < 512; i++) {
        float v = xf[i];
        if (!isfinite(v)) { mx = 1e30f; break; }
        mx = fmaxf(mx, fabsf(v));
    }
    g_flags[0] = (mx < 1e4f) ? 0 : 1;
    const int* ei = (const int*)edges;
    int odd_nonzero = 0;
    for (int i = 0; i < 2048; i += 2)
        if (ei[i + 1] != 0) odd_nonzero = 1;
    g_flags[1] = odd_nonzero ? 0 : 1;
}

// ---------------------------------------------------------------------------
__global__ void k_zero_adj() {
    size_t n = (size_t)NB * NODE * NODE;
    size_t stride = (size_t)gridDim.x * blockDim.x;
    for (size_t i = (size_t)blockIdx.x * blockDim.x + threadIdx.x; i < n; i += stride) {
        g_adjS[i] = 0.f;
        g_adjF[i] = 0.f;
    }
}

// ---------------------------------------------------------------------------
// Guarded adjacency build: adj[b][dst_local][src_local] += 1
// ---------------------------------------------------------------------------
__global__ void k_build_adj(const void* __restrict__ edges, int which) {
    float* adj = adjPtr(which);
    int e64 = g_flags[1];
    const int* e32 = (const int*)edges;
    const long long* e64p = (const long long*)edges;
    int i = blockIdx.x * blockDim.x + threadIdx.x;
    int stride = gridDim.x * blockDim.x;
    for (; i < EDGES; i += stride) {
        long long s, d;
        if (e64) { s = e64p[i]; d = e64p[EDGES + i]; }
        else     { s = e32[i];  d = e32[EDGES + i]; }
        if (s < 0 || s >= NN || d < 0 || d >= NN) continue;   // guard
        int b = (int)(d / NODE);
        if ((int)(s / NODE) != b) continue;                   // guard
        atomicAdd(&adj[(size_t)b * NODE * NODE +
                       (size_t)((int)d - b * NODE) * NODE + ((int)s - b * NODE)], 1.0f);
    }
}

// ---------------------------------------------------------------------------
__global__ void k_norm_adj(int which) {
    float* A = adjPtr(which) + (size_t)blockIdx.x * NODE * NODE;
    __shared__ float dinv[NODE];
    int tid = threadIdx.x;
    if (tid < NODE) {
        float s = 0.f;
        for (int k = 0; k < NODE; k++) s += A[tid * NODE + k];
        dinv[tid] = (s > 0.f) ? rsqrtf(s) : 0.f;
    }
    __syncthreads();
    for (int i = tid; i < NODE * NODE; i += blockDim.x) {
        int d = i / NODE;
        int s = i - d * NODE;
        A[i] = scrub(A[i] * dinv[d] * dinv[s]);
    }
}

// ---------------------------------------------------------------------------
// g_T[r][c] = sum_k X[r][k]*W[k][c], X [N][90], W [90][256] (flagged dtype)
// ---------------------------------------------------------------------------
template <int ROWS>
__global__ __launch_bounds__(HID) void k_gemm_in(const void* __restrict__ X,
                                                 const void* __restrict__ W) {
    int flag = g_flags[0];
    int r0 = blockIdx.x * ROWS;
    int c = threadIdx.x;
    float acc[ROWS];
#pragma unroll
    for (int r = 0; r < ROWS; r++) acc[r] = 0.f;
    for (int k = 0; k < NODE; k++) {
        float w = ldf(W, (size_t)k * HID + c, flag);
#pragma unroll
        for (int r = 0; r < ROWS; r++)
            acc[r] += ldf(X, (size_t)(r0 + r) * NODE + k, flag) * w;
    }
#pragma unroll
    for (int r = 0; r < ROWS; r++) g_T[(size_t)(r0 + r) * HID + c] = scrub(acc[r]);
}

// ---------------------------------------------------------------------------
// g_T[r][c] = sum_k X1[r][k]*W[k][c] (+ X2[r][k]*W[256+k][c]); X* fp32 scratch
// ---------------------------------------------------------------------------
template <int ROWS>
__global__ __launch_bounds__(HID) void k_gemm_h(int x1sel, int x2sel,
                                                const void* __restrict__ W) {
    int flag = g_flags[0];
    const float* X1 = selbuf(x1sel);
    const float* X2 = (x2sel >= 0) ? selbuf(x2sel) : nullptr;
    int r0 = blockIdx.x * ROWS;
    int c = threadIdx.x;
    float acc[ROWS];
#pragma unroll
    for (int r = 0; r < ROWS; r++) acc[r] = 0.f;
    for (int k = 0; k < HID; k++) {
        float w = ldf(W, (size_t)k * HID + c, flag);
#pragma unroll
        for (int r = 0; r < ROWS; r++)
            acc[r] += X1[(size_t)(r0 + r) * HID + k] * w;
    }
    if (X2) {
        for (int k = 0; k < HID; k++) {
            float w = ldf(W, (size_t)(HID + k) * HID + c, flag);
#pragma unroll
            for (int r = 0; r < ROWS; r++)
                acc[r] += X2[(size_t)(r0 + r) * HID + k] * w;
        }
    }
#pragma unroll
    for (int r = 0; r < ROWS; r++) g_T[(size_t)(r0 + r) * HID + c] = scrub(acc[r]);
}

// ---------------------------------------------------------------------------
// h[bn][c] = relu( sum_k Adj[b][n][k]*g_T[b*90+k][c] + bias[c] ) -> hsel + fp32 out
// ---------------------------------------------------------------------------
__global__ __launch_bounds__(HID) void k_aggregate(int which, const void* __restrict__ bias,
                                                   int hsel, float* __restrict__ outp) {
    int flag = g_flags[0];
    int bn = blockIdx.x;
    int b = bn / NODE;
    int c = threadIdx.x;
    const float* Arow = adjPtr(which) + (size_t)b * NODE * NODE + (size_t)(bn - b * NODE) * NODE;
    const float* Tg = g_T + (size_t)b * NODE * HID;
    float acc = ldf(bias, c, flag);
    for (int k = 0; k < NODE; k++)
        acc += Arow[k] * Tg[(size_t)k * HID + c];
    acc = scrub(fmaxf(acc, 0.f));
    selbuf(hsel)[(size_t)bn * HID + c] = acc;
    outp[(size_t)bn * 512 + c] = acc;
}

// ---------------------------------------------------------------------------
// g_A[b][n][m] = tanh_safe( dot(g_T[b,n,:], HF[b,m,:]) )
// ---------------------------------------------------------------------------
__global__ __launch_bounds__(HID) void k_scores(int hfsel) {
    int b = blockIdx.x;
    int tid = threadIdx.x;
    const float* HF = selbuf(hfsel) + (size_t)b * NODE * HID;
    const float* t2b = g_T + (size_t)b * NODE * HID;
    float* Ab = g_A + (size_t)b * NODE * NODE;
    __shared__ float trow[HID];
    for (int n = 0; n < NODE; n++) {
        __syncthreads();
        trow[tid] = t2b[(size_t)n * HID + tid];
        __syncthreads();
        if (tid < NODE) {
            float s = 0.f;
            for (int d = 0; d < HID; d++) s += trow[d] * HF[(size_t)tid * HID + d];
            Ab[n * NODE + tid] = tanh_safe(scrub(s));
        }
    }
}

// ---------------------------------------------------------------------------
// co_s[b][n][c] = sum_m softmax_m(A[b][n][:])[m] * F[b,m,c] -> csel + fp32 out
// ---------------------------------------------------------------------------
__global__ __launch_bounds__(HID) void k_cos(int fsel, int csel, float* __restrict__ outp) {
    int bn = blockIdx.x;
    int b = bn / NODE;
    int n = bn - b * NODE;
    int tid = threadIdx.x;
    __shared__ float arow[NODE];
    __shared__ float e[NODE];
    const float* Ab = g_A + (size_t)b * NODE * NODE;
    if (tid < NODE) arow[tid] = Ab[(size_t)n * NODE + tid];
    __syncthreads();
    float mx = -1e30f;
    for (int m = 0; m < NODE; m++) mx = fmaxf(mx, arow[m]);
    if (tid < NODE) e[tid] = __expf(fminf(fmaxf(arow[tid] - mx, -30.f), 30.f));
    __syncthreads();
    float denom = 0.f;
    for (int m = 0; m < NODE; m++) denom += e[m];
    float inv = 1.f / fmaxf(denom, 1e-20f);
    const float* Fb = selbuf(fsel) + (size_t)b * NODE * HID;
    float acc = 0.f;
    for (int m = 0; m < NODE; m++)
        acc += e[m] * Fb[(size_t)m * HID + tid];
    acc = scrub(acc * inv);
    selbuf(csel)[(size_t)bn * HID + tid] = acc;
    outp[(size_t)bn * 512 + tid] = acc;
}

// ---------------------------------------------------------------------------
// co_f[b][m][c] = sum_n softmax_n(A[b][:][m])[n] * S[b,n,c] -> csel + fp32 out
// ---------------------------------------------------------------------------
__global__ __launch_bounds__(HID) void k_cof(int ssel, int csel, float* __restrict__ outp) {
    int bm = blockIdx.x;
    int b = bm / NODE;
    int m = bm - b * NODE;
    int tid = threadIdx.x;
    __shared__ float acol[NODE];
    __shared__ float e[NODE];
    const float* Ab = g_A + (size_t)b * NODE * NODE;
    if (tid < NODE) acol[tid] = Ab[(size_t)tid * NODE + m];
    __syncthreads();
    float mx = -1e30f;
    for (int n = 0; n < NODE; n++) mx = fmaxf(mx, acol[n]);
    if (tid < NODE) e[tid] = __expf(fminf(fmaxf(acol[tid] - mx, -30.f), 30.f));
    __syncthreads();
    float denom = 0.f;
    for (int n = 0; n < NODE; n++) denom += e[n];
    float inv = 1.f / fmaxf(denom, 1e-20f);
    const float* Sb = selbuf(ssel) + (size_t)b * NODE * HID;
    float acc = 0.f;
    for (int n = 0; n < NODE; n++)
        acc += e[n] * Sb[(size_t)n * HID + tid];
    acc = scrub(acc * inv);
    selbuf(csel)[(size_t)bm * HID + tid] = acc;
    outp[(size_t)bm * 512 + tid] = acc;
}

// ---------------------------------------------------------------------------
extern "C" void kernel_launch(void* const* d_in, const int* in_sizes, int n_in,
                              void* d_out, int out_size, void* d_ws, size_t ws_size,
                              hipStream_t stream) {
    const void* x_sc = d_in[0];
    const void* e_sc = d_in[1];
    const void* x_fc = d_in[2];
    const void* e_fc = d_in[3];
    const void* W0 = d_in[4];
    const void* b0 = d_in[5];
    const void* W1 = d_in[6];
    const void* b1 = d_in[7];
    const void* Wa = d_in[8];

    const int N = NN;

    float* out = (float*)d_out;          // fp32 output!
    size_t os = (size_t)N * 512;
    float* x1s = out;
    float* x2s = out + os;
    float* x1f = out + 2 * os;
    float* x2f = out + 3 * os;

    k_detect<<<1, 64, 0, stream>>>(x_sc, e_sc);
    k_zero_adj<<<2048, 256, 0, stream>>>();
    k_build_adj<<<1024, 256, 0, stream>>>(e_sc, 0);
    k_build_adj<<<1024, 256, 0, stream>>>(e_fc, 1);
    k_norm_adj<<<NB, 128, 0, stream>>>(0);
    k_norm_adj<<<NB, 128, 0, stream>>>(1);

    // ---- layer 1 ----
    k_gemm_in<4><<<N / 4, HID, 0, stream>>>(x_sc, W0);
    k_aggregate<<<N, HID, 0, stream>>>(0, b0, /*hs*/0, x1s);
    k_gemm_in<4><<<N / 4, HID, 0, stream>>>(x_fc, W0);
    k_aggregate<<<N, HID, 0, stream>>>(1, b0, /*hf*/1, x1f);

    // ---- co-attention 1 ----
    k_gemm_h<4><<<N / 4, HID, 0, stream>>>(/*hs*/0, -1, Wa);
    k_scores<<<NB, HID, 0, stream>>>(/*hf*/1);
    k_cos<<<N, HID, 0, stream>>>(/*F=hf*/1, /*cs*/2, x1s + HID);
    k_cof<<<N, HID, 0, stream>>>(/*S=hs*/0, /*cf*/3, x1f + HID);

    // ---- layer 2 ----
    k_gemm_h<4><<<N / 4, HID, 0, stream>>>(/*hs*/0, /*cs*/2, W1);
    k_aggregate<<<N, HID, 0, stream>>>(0, b1, /*hs2*/0, x2s);
    k_gemm_h<4><<<N / 4, HID, 0, stream>>>(/*hf*/1, /*cf*/3, W1);
    k_aggregate<<<N, HID, 0, stream>>>(1, b1, /*hf2*/1, x2f);

    // ---- co-attention 2 ----
    k_gemm_h<4><<<N / 4, HID, 0, stream>>>(/*hs2*/0, -1, Wa);
    k_scores<<<NB, HID, 0, stream>>>(/*hf2*/1);
    k_cos<<<N, HID, 0, stream>>>(/*F=hf2*/1, /*cs*/2, x2s + HID);
    k_cof<<<N, HID, 0, stream>>>(/*S=hs2*/0, /*cf*/3, x2f + HID);
}

// Round 7
// 3621.568 us; speedup vs baseline: 1.3908x; 1.3908x over previous
//
#include <hip/hip_runtime.h>
#include <hip/hip_bf16.h>
#include <math.h>

#define NODE 90
#define HID 256
#define NB 512
#define NN (NB * NODE)
#define EDGES (NB * 2700)

typedef __hip_bfloat16 bf16;

__device__ __forceinline__ float scrub(float v) { return isfinite(v) ? v : 0.f; }

__device__ __forceinline__ float tanh_safe(float s) {
    s = fminf(fmaxf(s, -15.f), 15.f);
    float t = __expf(2.f * s);
    return (t - 1.f) / (t + 1.f);
}

// ---------------------------------------------------------------------------
// Module-scope fp32 scratch. d_ws unused.
// ---------------------------------------------------------------------------
__device__ float g_adjS[(size_t)NB * NODE * NODE];
__device__ float g_adjF[(size_t)NB * NODE * NODE];
__device__ float g_T[(size_t)NN * HID];
__device__ float g_hs[(size_t)NN * HID];
__device__ float g_hf[(size_t)NN * HID];
__device__ float g_cs[(size_t)NN * HID];
__device__ float g_cf[(size_t)NN * HID];
__device__ int g_flags[2];   // [1]: 0=edges int32, 1=edges int64

__device__ __forceinline__ float* adjPtr(int w) { return w ? g_adjF : g_adjS; }
__device__ __forceinline__ float* selbuf(int w) {
    switch (w) {
        case 0: return g_hs;
        case 1: return g_hf;
        case 2: return g_cs;
        default: return g_cf;
    }
}

// ---------------------------------------------------------------------------
__global__ void k_detect(const void* edges) {
    if (threadIdx.x != 0 || blockIdx.x != 0) return;
    const int* ei = (const int*)edges;
    int odd_nonzero = 0;
    for (int i = 0; i < 2048; i += 2)
        if (ei[i + 1] != 0) odd_nonzero = 1;
    g_flags[1] = odd_nonzero ? 0 : 1;
}

__global__ void k_zero_adj() {
    size_t n = (size_t)NB * NODE * NODE;
    size_t stride = (size_t)gridDim.x * blockDim.x;
    for (size_t i = (size_t)blockIdx.x * blockDim.x + threadIdx.x; i < n; i += stride) {
        g_adjS[i] = 0.f;
        g_adjF[i] = 0.f;
    }
}

// ---------------------------------------------------------------------------
__global__ void k_build_adj(const void* __restrict__ edges, int which) {
    float* adj = adjPtr(which);
    int e64 = g_flags[1];
    const int* e32 = (const int*)edges;
    const long long* e64p = (const long long*)edges;
    int i = blockIdx.x * blockDim.x + threadIdx.x;
    int stride = gridDim.x * blockDim.x;
    for (; i < EDGES; i += stride) {
        long long s, d;
        if (e64) { s = e64p[i]; d = e64p[EDGES + i]; }
        else     { s = e32[i];  d = e32[EDGES + i]; }
        if (s < 0 || s >= NN || d < 0 || d >= NN) continue;
        int b = (int)(d / NODE);
        if ((int)(s / NODE) != b) continue;
        atomicAdd(&adj[(size_t)b * NODE * NODE +
                       (size_t)((int)d - b * NODE) * NODE + ((int)s - b * NODE)], 1.0f);
    }
}

// ---------------------------------------------------------------------------
__global__ void k_norm_adj(int which) {
    float* A = adjPtr(which) + (size_t)blockIdx.x * NODE * NODE;
    __shared__ float dinv[NODE];
    int tid = threadIdx.x;
    if (tid < NODE) {
        float s = 0.f;
        for (int k = 0; k < NODE; k++) s += A[tid * NODE + k];
        dinv[tid] = (s > 0.f) ? rsqrtf(s) : 0.f;
    }
    __syncthreads();
    for (int i = tid; i < NODE * NODE; i += blockDim.x) {
        int d = i / NODE;
        int s = i - d * NODE;
        A[i] *= dinv[d] * dinv[s];
    }
}

// ---------------------------------------------------------------------------
// g_T[r][c] = sum_k X[r][k]*W[k][c]; X fp32 [N][90], W fp32 [90][256].
// X loads are wave-uniform (scalar pipe); W loads coalesced.
// ---------------------------------------------------------------------------
template <int ROWS>
__global__ __launch_bounds__(HID) void k_gemm_in(const float* __restrict__ X,
                                                 const float* __restrict__ W) {
    int r0 = blockIdx.x * ROWS;
    int c = threadIdx.x;
    float acc[ROWS];
#pragma unroll
    for (int r = 0; r < ROWS; r++) acc[r] = 0.f;
    for (int k = 0; k < NODE; k++) {
        float w = W[(size_t)k * HID + c];
#pragma unroll
        for (int r = 0; r < ROWS; r++)
            acc[r] = fmaf(X[(size_t)(r0 + r) * NODE + k], w, acc[r]);
    }
#pragma unroll
    for (int r = 0; r < ROWS; r++) g_T[(size_t)(r0 + r) * HID + c] = acc[r];
}

// ---------------------------------------------------------------------------
// g_T[r][c] = sum_k X1[r][k]*W[k][c] (+ X2[r][k]*W[256+k][c] if x2sel>=0).
// X rows via wave-uniform float4 (s_load_dwordx4); W coalesced.
// ---------------------------------------------------------------------------
template <int ROWS>
__global__ __launch_bounds__(HID) void k_gemm_h(int x1sel, int x2sel,
                                                const float* __restrict__ W) {
    int r0 = blockIdx.x * ROWS;
    int c = threadIdx.x;
    float acc[ROWS];
#pragma unroll
    for (int r = 0; r < ROWS; r++) acc[r] = 0.f;
    int halves = (x2sel >= 0) ? 2 : 1;
    for (int h = 0; h < halves; h++) {
        const float* X = selbuf(h ? x2sel : x1sel);
        const float* Wh = W + (size_t)h * HID * HID;
        for (int k = 0; k < HID; k += 4) {
            float w0 = Wh[(size_t)(k + 0) * HID + c];
            float w1 = Wh[(size_t)(k + 1) * HID + c];
            float w2 = Wh[(size_t)(k + 2) * HID + c];
            float w3 = Wh[(size_t)(k + 3) * HID + c];
#pragma unroll
            for (int r = 0; r < ROWS; r++) {
                const float4 xv = *reinterpret_cast<const float4*>(X + (size_t)(r0 + r) * HID + k);
                acc[r] = fmaf(xv.x, w0, acc[r]);
                acc[r] = fmaf(xv.y, w1, acc[r]);
                acc[r] = fmaf(xv.z, w2, acc[r]);
                acc[r] = fmaf(xv.w, w3, acc[r]);
            }
        }
    }
#pragma unroll
    for (int r = 0; r < ROWS; r++) g_T[(size_t)(r0 + r) * HID + c] = acc[r];
}

// ---------------------------------------------------------------------------
// h[bn][c] = relu( sum_k Adj[b][n][k]*g_T[b*90+k][c] + bias[c] ) -> hsel + out
// ---------------------------------------------------------------------------
__global__ __launch_bounds__(HID) void k_aggregate(int which, const float* __restrict__ bias,
                                                   int hsel, float* __restrict__ outp) {
    int bn = blockIdx.x;
    int b = bn / NODE;
    int c = threadIdx.x;
    const float* Arow = adjPtr(which) + (size_t)b * NODE * NODE + (size_t)(bn - b * NODE) * NODE;
    const float* Tg = g_T + (size_t)b * NODE * HID;
    float acc = bias[c];
    for (int k = 0; k < NODE; k++)
        acc = fmaf(Arow[k], Tg[(size_t)k * HID + c], acc);
    acc = fmaxf(acc, 0.f);
    selbuf(hsel)[(size_t)bn * HID + c] = acc;
    outp[(size_t)bn * 512 + c] = acc;
}

// ---------------------------------------------------------------------------
// Fused co-attention per graph (512 threads, ~128 KB LDS):
//   At = tanh(T2 @ HF^T); co_s = rowsoftmax(At) @ HF -> outS & cs
//   co_f = colsoftmax(At)^T @ HS -> outF & cf
// ---------------------------------------------------------------------------
#define CO_THREADS 512
__global__ __launch_bounds__(CO_THREADS) void k_coatt(int hfsel, int hssel,
                                                      float* __restrict__ outS,
                                                      float* __restrict__ outF,
                                                      int cssel, int cfsel) {
    __shared__ float hfl[NODE][257];     // 92,520 B: HF panel (later HS)
    __shared__ float At[NODE][92];       // 33,120 B: tanh scores
    __shared__ float prow[2][NODE];      // softmax rows being consumed
    __shared__ float rmax_[NODE], rinv_[NODE], cmax_[NODE], cinv_[NODE];

    int b = blockIdx.x;
    int tid = threadIdx.x;
    const float* HF = selbuf(hfsel) + (size_t)b * NODE * HID;
    const float* HS = selbuf(hssel) + (size_t)b * NODE * HID;
    const float* T2 = g_T + (size_t)b * NODE * HID;

    // stage HF into LDS (coalesced)
    for (int i = tid; i < NODE * HID; i += CO_THREADS)
        hfl[i >> 8][i & 255] = HF[i];
    __syncthreads();

    // ---- phase 1: scores At[n][m] = tanh(dot(T2[n], HF[m])) ----
    {
        int m = tid & 127;          // lane-consecutive -> LDS conflict-free (stride 257)
        int nof = tid >> 7;         // 0..3, wave-uniform
        for (int n0 = 0; n0 < NODE; n0 += 4) {
            int n = n0 + nof;
            if (m < NODE && n < NODE) {
                const float* t2r = T2 + (size_t)n * HID;   // wave-uniform -> s_loads
                float a0 = 0.f, a1 = 0.f;
                #pragma unroll 8
                for (int d = 0; d < HID; d += 2) {
                    a0 = fmaf(t2r[d], hfl[m][d], a0);
                    a1 = fmaf(t2r[d + 1], hfl[m][d + 1], a1);
                }
                At[n][m] = tanh_safe(a0 + a1);
            }
        }
    }
    __syncthreads();

    // ---- softmax stats: rows on waves 0-1, cols on waves 4-5 ----
    if (tid < NODE) {
        int n = tid;
        float mx = -2.f;
        for (int m = 0; m < NODE; m++) mx = fmaxf(mx, At[n][m]);
        float s = 0.f;
        for (int m = 0; m < NODE; m++) s += __expf(At[n][m] - mx);
        rmax_[n] = mx;
        rinv_[n] = 1.f / s;
    } else if (tid >= 256 && tid < 256 + NODE) {
        int m = tid - 256;
        float mx = -2.f;
        for (int n = 0; n < NODE; n++) mx = fmaxf(mx, At[n][m]);
        float s = 0.f;
        for (int n = 0; n < NODE; n++) s += __expf(At[n][m] - mx);
        cmax_[m] = mx;
        cinv_[m] = 1.f / s;
    }
    __syncthreads();

    // ---- phase 2: co_s rows (2 rows per iteration) ----
    {
        int c = tid & 255;
        int j = tid >> 8;   // 0 or 1
        for (int n0 = 0; n0 < NODE; n0 += 2) {
            if (tid < 2 * NODE) {
                int jj = tid / NODE, mm = tid - jj * NODE;
                prow[jj][mm] = __expf(At[n0 + jj][mm] - rmax_[n0 + jj]) * rinv_[n0 + jj];
            }
            __syncthreads();
            {
                int n = n0 + j;
                float a0 = 0.f, a1 = 0.f;
                #pragma unroll 6
                for (int m = 0; m < NODE; m += 2) {
                    a0 = fmaf(prow[j][m], hfl[m][c], a0);
                    a1 = fmaf(prow[j][m + 1], hfl[m + 1][c], a1);
                }
                float acc = a0 + a1;   // NODE=90 even
                size_t row = (size_t)(b * NODE + n);
                outS[row * 512 + c] = acc;
                selbuf(cssel)[row * HID + c] = acc;
            }
            __syncthreads();
        }
    }

    // ---- reload LDS panel with HS ----
    for (int i = tid; i < NODE * HID; i += CO_THREADS)
        hfl[i >> 8][i & 255] = HS[i];
    __syncthreads();

    // ---- phase 3: co_f rows (col softmax of At) ----
    {
        int c = tid & 255;
        int j = tid >> 8;
        for (int m0 = 0; m0 < NODE; m0 += 2) {
            if (tid < 2 * NODE) {
                int jj = tid / NODE, nn = tid - jj * NODE;
                prow[jj][nn] = __expf(At[nn][m0 + jj] - cmax_[m0 + jj]) * cinv_[m0 + jj];
            }
            __syncthreads();
            {
                int m = m0 + j;
                float a0 = 0.f, a1 = 0.f;
                #pragma unroll 6
                for (int n = 0; n < NODE; n += 2) {
                    a0 = fmaf(prow[j][n], hfl[n][c], a0);
                    a1 = fmaf(prow[j][n + 1], hfl[n + 1][c], a1);
                }
                float acc = a0 + a1;
                size_t row = (size_t)(b * NODE + m);
                outF[row * 512 + c] = acc;
                selbuf(cfsel)[row * HID + c] = acc;
            }
            __syncthreads();
        }
    }
}

// ---------------------------------------------------------------------------
extern "C" void kernel_launch(void* const* d_in, const int* in_sizes, int n_in,
                              void* d_out, int out_size, void* d_ws, size_t ws_size,
                              hipStream_t stream) {
    const float* x_sc = (const float*)d_in[0];
    const void* e_sc = d_in[1];
    const float* x_fc = (const float*)d_in[2];
    const void* e_fc = d_in[3];
    const float* W0 = (const float*)d_in[4];
    const float* b0 = (const float*)d_in[5];
    const float* W1 = (const float*)d_in[6];
    const float* b1 = (const float*)d_in[7];
    const float* Wa = (const float*)d_in[8];

    const int N = NN;

    float* out = (float*)d_out;
    size_t os = (size_t)N * 512;
    float* x1s = out;
    float* x2s = out + os;
    float* x1f = out + 2 * os;
    float* x2f = out + 3 * os;

    k_detect<<<1, 64, 0, stream>>>(e_sc);
    k_zero_adj<<<2048, 256, 0, stream>>>();
    k_build_adj<<<1024, 256, 0, stream>>>(e_sc, 0);
    k_build_adj<<<1024, 256, 0, stream>>>(e_fc, 1);
    k_norm_adj<<<NB, 128, 0, stream>>>(0);
    k_norm_adj<<<NB, 128, 0, stream>>>(1);

    // ---- layer 1 ----
    k_gemm_in<16><<<N / 16, HID, 0, stream>>>(x_sc, W0);
    k_aggregate<<<N, HID, 0, stream>>>(0, b0, /*hs*/0, x1s);
    k_gemm_in<16><<<N / 16, HID, 0, stream>>>(x_fc, W0);
    k_aggregate<<<N, HID, 0, stream>>>(1, b0, /*hf*/1, x1f);

    // ---- co-attention 1 ----
    k_gemm_h<16><<<N / 16, HID, 0, stream>>>(/*hs*/0, -1, Wa);
    k_coatt<<<NB, CO_THREADS, 0, stream>>>(/*hf*/1, /*hs*/0, x1s + HID, x1f + HID,
                                           /*cs*/2, /*cf*/3);

    // ---- layer 2 ----
    k_gemm_h<16><<<N / 16, HID, 0, stream>>>(/*hs*/0, /*cs*/2, W1);
    k_aggregate<<<N, HID, 0, stream>>>(0, b1, /*hs2*/0, x2s);
    k_gemm_h<16><<<N / 16, HID, 0, stream>>>(/*hf*/1, /*cf*/3, W1);
    k_aggregate<<<N, HID, 0, stream>>>(1, b1, /*hf2*/1, x2f);

    // ---- co-attention 2 ----
    k_gemm_h<16><<<N / 16, HID, 0, stream>>>(/*hs2*/0, -1, Wa);
    k_coatt<<<NB, CO_THREADS, 0, stream>>>(/*hf2*/1, /*hs2*/0, x2s + HID, x2f + HID,
                                           /*cs*/2, /*cf*/3);
}

// Round 8
// 2140.666 us; speedup vs baseline: 2.3530x; 1.6918x over previous
//
#include <hip/hip_runtime.h>
#include <hip/hip_bf16.h>
#include <math.h>

#define NODE 90
#define HID 256
#define NB 512
#define NN (NB * NODE)
#define EDGES (NB * 2700)

__device__ __forceinline__ float scrub(float v) { return isfinite(v) ? v : 0.f; }

__device__ __forceinline__ float tanh_safe(float s) {
    s = fminf(fmaxf(s, -15.f), 15.f);
    float t = __expf(2.f * s);
    return (t - 1.f) / (t + 1.f);
}

// ---------------------------------------------------------------------------
// Module-scope fp32 scratch. d_ws unused.
// ---------------------------------------------------------------------------
__device__ float g_adjS[(size_t)NB * NODE * NODE];
__device__ float g_adjF[(size_t)NB * NODE * NODE];
__device__ float g_T[(size_t)NN * HID];
__device__ float g_hs[(size_t)NN * HID];
__device__ float g_hf[(size_t)NN * HID];
__device__ float g_cs[(size_t)NN * HID];
__device__ float g_cf[(size_t)NN * HID];
__device__ int g_flags[2];

__device__ __forceinline__ float* adjPtr(int w) { return w ? g_adjF : g_adjS; }
__device__ __forceinline__ float* selbuf(int w) {
    switch (w) {
        case 0: return g_hs;
        case 1: return g_hf;
        case 2: return g_cs;
        default: return g_cf;
    }
}

// ---------------------------------------------------------------------------
__global__ void k_detect(const void* edges) {
    if (threadIdx.x != 0 || blockIdx.x != 0) return;
    const int* ei = (const int*)edges;
    int odd_nonzero = 0;
    for (int i = 0; i < 2048; i += 2)
        if (ei[i + 1] != 0) odd_nonzero = 1;
    g_flags[1] = odd_nonzero ? 0 : 1;
}

__global__ void k_zero_adj() {
    size_t n = (size_t)NB * NODE * NODE;
    size_t stride = (size_t)gridDim.x * blockDim.x;
    for (size_t i = (size_t)blockIdx.x * blockDim.x + threadIdx.x; i < n; i += stride) {
        g_adjS[i] = 0.f;
        g_adjF[i] = 0.f;
    }
}

// ---------------------------------------------------------------------------
__global__ void k_build_adj(const void* __restrict__ edges, int which) {
    float* adj = adjPtr(which);
    int e64 = g_flags[1];
    const int* e32 = (const int*)edges;
    const long long* e64p = (const long long*)edges;
    int i = blockIdx.x * blockDim.x + threadIdx.x;
    int stride = gridDim.x * blockDim.x;
    for (; i < EDGES; i += stride) {
        long long s, d;
        if (e64) { s = e64p[i]; d = e64p[EDGES + i]; }
        else     { s = e32[i];  d = e32[EDGES + i]; }
        if (s < 0 || s >= NN || d < 0 || d >= NN) continue;
        int b = (int)(d / NODE);
        if ((int)(s / NODE) != b) continue;
        atomicAdd(&adj[(size_t)b * NODE * NODE +
                       (size_t)((int)d - b * NODE) * NODE + ((int)s - b * NODE)], 1.0f);
    }
}

// ---------------------------------------------------------------------------
__global__ void k_norm_adj(int which) {
    float* A = adjPtr(which) + (size_t)blockIdx.x * NODE * NODE;
    __shared__ float dinv[NODE];
    int tid = threadIdx.x;
    if (tid < NODE) {
        float s = 0.f;
        for (int k = 0; k < NODE; k++) s += A[tid * NODE + k];
        dinv[tid] = (s > 0.f) ? rsqrtf(s) : 0.f;
    }
    __syncthreads();
    for (int i = tid; i < NODE * NODE; i += blockDim.x) {
        int d = i / NODE;
        int s = i - d * NODE;
        A[i] *= dinv[d] * dinv[s];
    }
}

// ---------------------------------------------------------------------------
// Tiled fp32 GEMM: g_T[M][256] = X @ W.
// X: either external ptr (ldx_ext row stride) or selbuf(x1sel) [M][256]
// (+ selbuf(x2sel) as rows 256.. of a concat for K=512). W row-major [K][256].
// Tile 128x128, BK=16, 256 threads, 8x8 micro-tile.
// ---------------------------------------------------------------------------
#define BM 128
#define BN 128
#define BKc 16
__global__ __launch_bounds__(256) void k_gemm_tile(const float* __restrict__ Xext,
                                                   int x1sel, int x2sel,
                                                   int K, int ldx_ext,
                                                   const float* __restrict__ W) {
    __shared__ float As[BKc][BM + 4];   // [kk][r]
    __shared__ float Bs[BKc][BN + 4];   // [kk][c]
    int tid = threadIdx.x;
    int id = blockIdx.x;
    int bm = id >> 1, bn = id & 1;
    int r0 = bm * BM, c0 = bn * BN;
    int ti = tid & 15, tj = tid >> 4;   // rows 8*ti, cols 8*tj

    float acc[8][8];
#pragma unroll
    for (int i = 0; i < 8; i++)
#pragma unroll
        for (int j = 0; j < 8; j++) acc[i][j] = 0.f;

    for (int k0 = 0; k0 < K; k0 += BKc) {
        int kl = K - k0; if (kl > BKc) kl = BKc;
        const float* Xb; int xc, ldx;
        if (x1sel < 0)                  { Xb = Xext;           xc = k0;       ldx = ldx_ext; }
        else if (x2sel >= 0 && k0 >= HID) { Xb = selbuf(x2sel); xc = k0 - HID; ldx = HID; }
        else                            { Xb = selbuf(x1sel);  xc = k0;       ldx = HID; }

        __syncthreads();
        // stage A transposed: As[kk][r] = X[r0+r][xc+kk]
        for (int i = tid; i < BM * BKc; i += 256) {
            int r = i >> 4, kk = i & 15;
            As[kk][r] = (kk < kl) ? Xb[(size_t)(r0 + r) * ldx + xc + kk] : 0.f;
        }
        // stage B: Bs[kk][c] = W[k0+kk][c0+c]  (float4)
        for (int i = tid; i < BKc * BN / 4; i += 256) {
            int kk = i >> 5;
            int c4 = (i & 31) << 2;
            float4 v = make_float4(0.f, 0.f, 0.f, 0.f);
            if (kk < kl) v = *(const float4*)&W[(size_t)(k0 + kk) * HID + c0 + c4];
            *(float4*)&Bs[kk][c4] = v;
        }
        __syncthreads();

#pragma unroll
        for (int kk = 0; kk < BKc; kk++) {
            float4 a0 = *(const float4*)&As[kk][8 * ti];
            float4 a1 = *(const float4*)&As[kk][8 * ti + 4];
            float4 b0 = *(const float4*)&Bs[kk][8 * tj];
            float4 b1 = *(const float4*)&Bs[kk][8 * tj + 4];
            float av[8] = {a0.x, a0.y, a0.z, a0.w, a1.x, a1.y, a1.z, a1.w};
            float bv[8] = {b0.x, b0.y, b0.z, b0.w, b1.x, b1.y, b1.z, b1.w};
#pragma unroll
            for (int i = 0; i < 8; i++)
#pragma unroll
                for (int j = 0; j < 8; j++)
                    acc[i][j] = fmaf(av[i], bv[j], acc[i][j]);
        }
    }

#pragma unroll
    for (int i = 0; i < 8; i++) {
        size_t r = (size_t)(r0 + 8 * ti + i);
        float4 o0 = make_float4(acc[i][0], acc[i][1], acc[i][2], acc[i][3]);
        float4 o1 = make_float4(acc[i][4], acc[i][5], acc[i][6], acc[i][7]);
        *(float4*)&g_T[r * HID + c0 + 8 * tj] = o0;
        *(float4*)&g_T[r * HID + c0 + 8 * tj + 4] = o1;
    }
}

// ---------------------------------------------------------------------------
// Per-graph aggregate: out[b,n,c] = relu( sum_k Adj[b][n][k]*g_T[b,k,c] + bias[c] )
// grid = NB*2 (graph x col-half), 256 threads, 6x8 micro-tile, AdjT in LDS.
// ---------------------------------------------------------------------------
__global__ __launch_bounds__(256) void k_agg_tile(int which, const float* __restrict__ bias,
                                                  int hsel, float* __restrict__ outp) {
    __shared__ float AdjT[NODE][102];   // [k][n], pad 102 -> conflict-free b64 reads
    int tid = threadIdx.x;
    int b = blockIdx.x >> 1;
    int c0 = (blockIdx.x & 1) * 128;
    const float* Adj = adjPtr(which) + (size_t)b * NODE * NODE;

    for (int i = tid; i < NODE * NODE; i += 256) {
        int n = i / NODE, k = i - n * NODE;
        AdjT[k][n] = Adj[i];
    }
    // zero the row-pad (rows 90..95 read by ti=15 lanes)
    for (int i = tid; i < NODE * 12; i += 256) {
        int k = i / 12, n = NODE + (i % 12);
        AdjT[k][n] = 0.f;
    }
    __syncthreads();

    int ti = tid & 15, tj = tid >> 4;
    int rbase = 6 * ti;              // rows rbase..rbase+5 (>=90 masked at write)
    int cc = c0 + 8 * tj;
    const float* Tg = g_T + (size_t)b * NODE * HID;

    float acc[6][8];
#pragma unroll
    for (int i = 0; i < 6; i++)
#pragma unroll
        for (int j = 0; j < 8; j++) acc[i][j] = 0.f;

#pragma unroll 2
    for (int k = 0; k < NODE; k++) {
        float4 t0 = *(const float4*)&Tg[(size_t)k * HID + cc];
        float4 t1 = *(const float4*)&Tg[(size_t)k * HID + cc + 4];
        float bv[8] = {t0.x, t0.y, t0.z, t0.w, t1.x, t1.y, t1.z, t1.w};
        float2 a01 = *(const float2*)&AdjT[k][rbase];
        float2 a23 = *(const float2*)&AdjT[k][rbase + 2];
        float2 a45 = *(const float2*)&AdjT[k][rbase + 4];
        float av[6] = {a01.x, a01.y, a23.x, a23.y, a45.x, a45.y};
#pragma unroll
        for (int i = 0; i < 6; i++)
#pragma unroll
            for (int j = 0; j < 8; j++)
                acc[i][j] = fmaf(av[i], bv[j], acc[i][j]);
    }

    float bb[8];
#pragma unroll
    for (int j = 0; j < 8; j++) bb[j] = bias[cc + j];

    float* hdst = selbuf(hsel);
#pragma unroll
    for (int i = 0; i < 6; i++) {
        int n = rbase + i;
        if (n < NODE) {
            size_t row = (size_t)(b * NODE + n);
            float v[8];
#pragma unroll
            for (int j = 0; j < 8; j++) v[j] = fmaxf(acc[i][j] + bb[j], 0.f);
            float4 o0 = make_float4(v[0], v[1], v[2], v[3]);
            float4 o1 = make_float4(v[4], v[5], v[6], v[7]);
            *(float4*)&hdst[row * HID + cc] = o0;
            *(float4*)&hdst[row * HID + cc + 4] = o1;
            *(float4*)&outp[row * 512 + cc] = o0;
            *(float4*)&outp[row * 512 + cc + 4] = o1;
        }
    }
}

// ---------------------------------------------------------------------------
// Fused co-attention per graph (512 threads, ~128 KB LDS). (unchanged, passing)
// ---------------------------------------------------------------------------
#define CO_THREADS 512
__global__ __launch_bounds__(CO_THREADS) void k_coatt(int hfsel, int hssel,
                                                      float* __restrict__ outS,
                                                      float* __restrict__ outF,
                                                      int cssel, int cfsel) {
    __shared__ float hfl[NODE][257];
    __shared__ float At[NODE][92];
    __shared__ float prow[2][NODE];
    __shared__ float rmax_[NODE], rinv_[NODE], cmax_[NODE], cinv_[NODE];

    int b = blockIdx.x;
    int tid = threadIdx.x;
    const float* HF = selbuf(hfsel) + (size_t)b * NODE * HID;
    const float* HS = selbuf(hssel) + (size_t)b * NODE * HID;
    const float* T2 = g_T + (size_t)b * NODE * HID;

    for (int i = tid; i < NODE * HID; i += CO_THREADS)
        hfl[i >> 8][i & 255] = HF[i];
    __syncthreads();

    {
        int m = tid & 127;
        int nof = tid >> 7;
        for (int n0 = 0; n0 < NODE; n0 += 4) {
            int n = n0 + nof;
            if (m < NODE && n < NODE) {
                const float* t2r = T2 + (size_t)n * HID;
                float a0 = 0.f, a1 = 0.f;
                #pragma unroll 8
                for (int d = 0; d < HID; d += 2) {
                    a0 = fmaf(t2r[d], hfl[m][d], a0);
                    a1 = fmaf(t2r[d + 1], hfl[m][d + 1], a1);
                }
                At[n][m] = tanh_safe(a0 + a1);
            }
        }
    }
    __syncthreads();

    if (tid < NODE) {
        int n = tid;
        float mx = -2.f;
        for (int m = 0; m < NODE; m++) mx = fmaxf(mx, At[n][m]);
        float s = 0.f;
        for (int m = 0; m < NODE; m++) s += __expf(At[n][m] - mx);
        rmax_[n] = mx;
        rinv_[n] = 1.f / s;
    } else if (tid >= 256 && tid < 256 + NODE) {
        int m = tid - 256;
        float mx = -2.f;
        for (int n = 0; n < NODE; n++) mx = fmaxf(mx, At[n][m]);
        float s = 0.f;
        for (int n = 0; n < NODE; n++) s += __expf(At[n][m] - mx);
        cmax_[m] = mx;
        cinv_[m] = 1.f / s;
    }
    __syncthreads();

    {
        int c = tid & 255;
        int j = tid >> 8;
        for (int n0 = 0; n0 < NODE; n0 += 2) {
            if (tid < 2 * NODE) {
                int jj = tid / NODE, mm = tid - jj * NODE;
                prow[jj][mm] = __expf(At[n0 + jj][mm] - rmax_[n0 + jj]) * rinv_[n0 + jj];
            }
            __syncthreads();
            {
                int n = n0 + j;
                float a0 = 0.f, a1 = 0.f;
                #pragma unroll 6
                for (int m = 0; m < NODE; m += 2) {
                    a0 = fmaf(prow[j][m], hfl[m][c], a0);
                    a1 = fmaf(prow[j][m + 1], hfl[m + 1][c], a1);
                }
                float acc = a0 + a1;
                size_t row = (size_t)(b * NODE + n);
                outS[row * 512 + c] = acc;
                selbuf(cssel)[row * HID + c] = acc;
            }
            __syncthreads();
        }
    }

    for (int i = tid; i < NODE * HID; i += CO_THREADS)
        hfl[i >> 8][i & 255] = HS[i];
    __syncthreads();

    {
        int c = tid & 255;
        int j = tid >> 8;
        for (int m0 = 0; m0 < NODE; m0 += 2) {
            if (tid < 2 * NODE) {
                int jj = tid / NODE, nn = tid - jj * NODE;
                prow[jj][nn] = __expf(At[nn][m0 + jj] - cmax_[m0 + jj]) * cinv_[m0 + jj];
            }
            __syncthreads();
            {
                int m = m0 + j;
                float a0 = 0.f, a1 = 0.f;
                #pragma unroll 6
                for (int n = 0; n < NODE; n += 2) {
                    a0 = fmaf(prow[j][n], hfl[n][c], a0);
                    a1 = fmaf(prow[j][n + 1], hfl[n + 1][c], a1);
                }
                float acc = a0 + a1;
                size_t row = (size_t)(b * NODE + m);
                outF[row * 512 + c] = acc;
                selbuf(cfsel)[row * HID + c] = acc;
            }
            __syncthreads();
        }
    }
}

// ---------------------------------------------------------------------------
extern "C" void kernel_launch(void* const* d_in, const int* in_sizes, int n_in,
                              void* d_out, int out_size, void* d_ws, size_t ws_size,
                              hipStream_t stream) {
    const float* x_sc = (const float*)d_in[0];
    const void* e_sc = d_in[1];
    const float* x_fc = (const float*)d_in[2];
    const void* e_fc = d_in[3];
    const float* W0 = (const float*)d_in[4];
    const float* b0 = (const float*)d_in[5];
    const float* W1 = (const float*)d_in[6];
    const float* b1 = (const float*)d_in[7];
    const float* Wa = (const float*)d_in[8];

    float* out = (float*)d_out;
    size_t os = (size_t)NN * 512;
    float* x1s = out;
    float* x2s = out + os;
    float* x1f = out + 2 * os;
    float* x2f = out + 3 * os;

    const int GEMM_GRID = (NN / BM) * 2;   // 720

    k_detect<<<1, 64, 0, stream>>>(e_sc);
    k_zero_adj<<<2048, 256, 0, stream>>>();
    k_build_adj<<<1024, 256, 0, stream>>>(e_sc, 0);
    k_build_adj<<<1024, 256, 0, stream>>>(e_fc, 1);
    k_norm_adj<<<NB, 128, 0, stream>>>(0);
    k_norm_adj<<<NB, 128, 0, stream>>>(1);

    // ---- layer 1 ----
    k_gemm_tile<<<GEMM_GRID, 256, 0, stream>>>(x_sc, -1, -1, NODE, NODE, W0);
    k_agg_tile<<<NB * 2, 256, 0, stream>>>(0, b0, /*hs*/0, x1s);
    k_gemm_tile<<<GEMM_GRID, 256, 0, stream>>>(x_fc, -1, -1, NODE, NODE, W0);
    k_agg_tile<<<NB * 2, 256, 0, stream>>>(1, b0, /*hf*/1, x1f);

    // ---- co-attention 1 ----
    k_gemm_tile<<<GEMM_GRID, 256, 0, stream>>>(nullptr, /*hs*/0, -1, HID, HID, Wa);
    k_coatt<<<NB, CO_THREADS, 0, stream>>>(/*hf*/1, /*hs*/0, x1s + HID, x1f + HID, 2, 3);

    // ---- layer 2 ----
    k_gemm_tile<<<GEMM_GRID, 256, 0, stream>>>(nullptr, /*hs*/0, /*cs*/2, 512, HID, W1);
    k_agg_tile<<<NB * 2, 256, 0, stream>>>(0, b1, /*hs2*/0, x2s);
    k_gemm_tile<<<GEMM_GRID, 256, 0, stream>>>(nullptr, /*hf*/1, /*cf*/3, 512, HID, W1);
    k_agg_tile<<<NB * 2, 256, 0, stream>>>(1, b1, /*hf2*/1, x2f);

    // ---- co-attention 2 ----
    k_gemm_tile<<<GEMM_GRID, 256, 0, stream>>>(nullptr, /*hs2*/0, -1, HID, HID, Wa);
    k_coatt<<<NB, CO_THREADS, 0, stream>>>(/*hf2*/1, /*hs2*/0, x2s + HID, x2f + HID, 2, 3);
}

// Round 9
// 1548.645 us; speedup vs baseline: 3.2525x; 1.3823x over previous
//
#include <hip/hip_runtime.h>
#include <hip/hip_bf16.h>
#include <math.h>

#define NODE 90
#define HID 256
#define NB 512
#define NN (NB * NODE)
#define EDGES (NB * 2700)

__device__ __forceinline__ float scrub(float v) { return isfinite(v) ? v : 0.f; }

__device__ __forceinline__ float tanh_safe(float s) {
    s = fminf(fmaxf(s, -15.f), 15.f);
    float t = __expf(2.f * s);
    return (t - 1.f) / (t + 1.f);
}

// ---------------------------------------------------------------------------
// Module-scope fp32 scratch. d_ws unused.
// ---------------------------------------------------------------------------
__device__ float g_adjS[(size_t)NB * NODE * NODE];
__device__ float g_adjF[(size_t)NB * NODE * NODE];
__device__ float g_T[(size_t)NN * HID];
__device__ float g_hs[(size_t)NN * HID];
__device__ float g_hf[(size_t)NN * HID];
__device__ float g_cs[(size_t)NN * HID];
__device__ float g_cf[(size_t)NN * HID];
__device__ int g_flags[2];

__device__ __forceinline__ float* adjPtr(int w) { return w ? g_adjF : g_adjS; }
__device__ __forceinline__ float* selbuf(int w) {
    switch (w) {
        case 0: return g_hs;
        case 1: return g_hf;
        case 2: return g_cs;
        default: return g_cf;
    }
}

// ---------------------------------------------------------------------------
__global__ void k_detect(const void* edges) {
    if (threadIdx.x != 0 || blockIdx.x != 0) return;
    const int* ei = (const int*)edges;
    int odd_nonzero = 0;
    for (int i = 0; i < 2048; i += 2)
        if (ei[i + 1] != 0) odd_nonzero = 1;
    g_flags[1] = odd_nonzero ? 0 : 1;
}

__global__ void k_zero_adj() {
    size_t n = (size_t)NB * NODE * NODE;
    size_t stride = (size_t)gridDim.x * blockDim.x;
    for (size_t i = (size_t)blockIdx.x * blockDim.x + threadIdx.x; i < n; i += stride) {
        g_adjS[i] = 0.f;
        g_adjF[i] = 0.f;
    }
}

// ---------------------------------------------------------------------------
__global__ void k_build_adj(const void* __restrict__ edges, int which) {
    float* adj = adjPtr(which);
    int e64 = g_flags[1];
    const int* e32 = (const int*)edges;
    const long long* e64p = (const long long*)edges;
    int i = blockIdx.x * blockDim.x + threadIdx.x;
    int stride = gridDim.x * blockDim.x;
    for (; i < EDGES; i += stride) {
        long long s, d;
        if (e64) { s = e64p[i]; d = e64p[EDGES + i]; }
        else     { s = e32[i];  d = e32[EDGES + i]; }
        if (s < 0 || s >= NN || d < 0 || d >= NN) continue;
        int b = (int)(d / NODE);
        if ((int)(s / NODE) != b) continue;
        atomicAdd(&adj[(size_t)b * NODE * NODE +
                       (size_t)((int)d - b * NODE) * NODE + ((int)s - b * NODE)], 1.0f);
    }
}

// ---------------------------------------------------------------------------
__global__ void k_norm_adj(int which) {
    float* A = adjPtr(which) + (size_t)blockIdx.x * NODE * NODE;
    __shared__ float dinv[NODE];
    int tid = threadIdx.x;
    if (tid < NODE) {
        float s = 0.f;
        for (int k = 0; k < NODE; k++) s += A[tid * NODE + k];
        dinv[tid] = (s > 0.f) ? rsqrtf(s) : 0.f;
    }
    __syncthreads();
    for (int i = tid; i < NODE * NODE; i += blockDim.x) {
        int d = i / NODE;
        int s = i - d * NODE;
        A[i] *= dinv[d] * dinv[s];
    }
}

// ---------------------------------------------------------------------------
// Tiled fp32 GEMM: g_T[M][256] = X @ W.  (unchanged from round 8)
// ---------------------------------------------------------------------------
#define BM 128
#define BN 128
#define BKc 16
__global__ __launch_bounds__(256) void k_gemm_tile(const float* __restrict__ Xext,
                                                   int x1sel, int x2sel,
                                                   int K, int ldx_ext,
                                                   const float* __restrict__ W) {
    __shared__ float As[BKc][BM + 4];
    __shared__ float Bs[BKc][BN + 4];
    int tid = threadIdx.x;
    int id = blockIdx.x;
    int bm = id >> 1, bn = id & 1;
    int r0 = bm * BM, c0 = bn * BN;
    int ti = tid & 15, tj = tid >> 4;

    float acc[8][8];
#pragma unroll
    for (int i = 0; i < 8; i++)
#pragma unroll
        for (int j = 0; j < 8; j++) acc[i][j] = 0.f;

    for (int k0 = 0; k0 < K; k0 += BKc) {
        int kl = K - k0; if (kl > BKc) kl = BKc;
        const float* Xb; int xc, ldx;
        if (x1sel < 0)                  { Xb = Xext;           xc = k0;       ldx = ldx_ext; }
        else if (x2sel >= 0 && k0 >= HID) { Xb = selbuf(x2sel); xc = k0 - HID; ldx = HID; }
        else                            { Xb = selbuf(x1sel);  xc = k0;       ldx = HID; }

        __syncthreads();
        for (int i = tid; i < BM * BKc; i += 256) {
            int r = i >> 4, kk = i & 15;
            As[kk][r] = (kk < kl) ? Xb[(size_t)(r0 + r) * ldx + xc + kk] : 0.f;
        }
        for (int i = tid; i < BKc * BN / 4; i += 256) {
            int kk = i >> 5;
            int c4 = (i & 31) << 2;
            float4 v = make_float4(0.f, 0.f, 0.f, 0.f);
            if (kk < kl) v = *(const float4*)&W[(size_t)(k0 + kk) * HID + c0 + c4];
            *(float4*)&Bs[kk][c4] = v;
        }
        __syncthreads();

#pragma unroll
        for (int kk = 0; kk < BKc; kk++) {
            float4 a0 = *(const float4*)&As[kk][8 * ti];
            float4 a1 = *(const float4*)&As[kk][8 * ti + 4];
            float4 b0 = *(const float4*)&Bs[kk][8 * tj];
            float4 b1 = *(const float4*)&Bs[kk][8 * tj + 4];
            float av[8] = {a0.x, a0.y, a0.z, a0.w, a1.x, a1.y, a1.z, a1.w};
            float bv[8] = {b0.x, b0.y, b0.z, b0.w, b1.x, b1.y, b1.z, b1.w};
#pragma unroll
            for (int i = 0; i < 8; i++)
#pragma unroll
                for (int j = 0; j < 8; j++)
                    acc[i][j] = fmaf(av[i], bv[j], acc[i][j]);
        }
    }

#pragma unroll
    for (int i = 0; i < 8; i++) {
        size_t r = (size_t)(r0 + 8 * ti + i);
        float4 o0 = make_float4(acc[i][0], acc[i][1], acc[i][2], acc[i][3]);
        float4 o1 = make_float4(acc[i][4], acc[i][5], acc[i][6], acc[i][7]);
        *(float4*)&g_T[r * HID + c0 + 8 * tj] = o0;
        *(float4*)&g_T[r * HID + c0 + 8 * tj + 4] = o1;
    }
}

// ---------------------------------------------------------------------------
// Per-graph aggregate (unchanged from round 8)
// ---------------------------------------------------------------------------
__global__ __launch_bounds__(256) void k_agg_tile(int which, const float* __restrict__ bias,
                                                  int hsel, float* __restrict__ outp) {
    __shared__ float AdjT[NODE][102];
    int tid = threadIdx.x;
    int b = blockIdx.x >> 1;
    int c0 = (blockIdx.x & 1) * 128;
    const float* Adj = adjPtr(which) + (size_t)b * NODE * NODE;

    for (int i = tid; i < NODE * NODE; i += 256) {
        int n = i / NODE, k = i - n * NODE;
        AdjT[k][n] = Adj[i];
    }
    for (int i = tid; i < NODE * 12; i += 256) {
        int k = i / 12, n = NODE + (i % 12);
        AdjT[k][n] = 0.f;
    }
    __syncthreads();

    int ti = tid & 15, tj = tid >> 4;
    int rbase = 6 * ti;
    int cc = c0 + 8 * tj;
    const float* Tg = g_T + (size_t)b * NODE * HID;

    float acc[6][8];
#pragma unroll
    for (int i = 0; i < 6; i++)
#pragma unroll
        for (int j = 0; j < 8; j++) acc[i][j] = 0.f;

#pragma unroll 2
    for (int k = 0; k < NODE; k++) {
        float4 t0 = *(const float4*)&Tg[(size_t)k * HID + cc];
        float4 t1 = *(const float4*)&Tg[(size_t)k * HID + cc + 4];
        float bv[8] = {t0.x, t0.y, t0.z, t0.w, t1.x, t1.y, t1.z, t1.w};
        float2 a01 = *(const float2*)&AdjT[k][rbase];
        float2 a23 = *(const float2*)&AdjT[k][rbase + 2];
        float2 a45 = *(const float2*)&AdjT[k][rbase + 4];
        float av[6] = {a01.x, a01.y, a23.x, a23.y, a45.x, a45.y};
#pragma unroll
        for (int i = 0; i < 6; i++)
#pragma unroll
            for (int j = 0; j < 8; j++)
                acc[i][j] = fmaf(av[i], bv[j], acc[i][j]);
    }

    float bb[8];
#pragma unroll
    for (int j = 0; j < 8; j++) bb[j] = bias[cc + j];

    float* hdst = selbuf(hsel);
#pragma unroll
    for (int i = 0; i < 6; i++) {
        int n = rbase + i;
        if (n < NODE) {
            size_t row = (size_t)(b * NODE + n);
            float v[8];
#pragma unroll
            for (int j = 0; j < 8; j++) v[j] = fmaxf(acc[i][j] + bb[j], 0.f);
            float4 o0 = make_float4(v[0], v[1], v[2], v[3]);
            float4 o1 = make_float4(v[4], v[5], v[6], v[7]);
            *(float4*)&hdst[row * HID + cc] = o0;
            *(float4*)&hdst[row * HID + cc + 4] = o1;
            *(float4*)&outp[row * 512 + cc] = o0;
            *(float4*)&outp[row * 512 + cc + 4] = o1;
        }
    }
}

// ---------------------------------------------------------------------------
// Fused co-attention per graph — register-micro-tiled, barrier-free phases.
//   phase 1: At[n][m] = tanh(dot(T2[n], HF[m]))     (3x6 reg tile, T2 chunked)
//   stats:   row max/inv + fn[n]=Σexp(At[n][:]);  col gm[m]=1/Σexp(At[:][m])
//   P := rowsoftmax(At) in place
//   phase 2: co_s[n] = P @ HF                        (12x4 reg tile)
//   P := P * fn[n];  reload panel with HS
//   phase 3: co_f[m] = gm[m] * (P^T @ HS)            (12x4 reg tile)
// ---------------------------------------------------------------------------
#define CO_THREADS 512
__global__ __launch_bounds__(CO_THREADS, 1) void k_coatt(int hfsel, int hssel,
                                                         float* __restrict__ outS,
                                                         float* __restrict__ outF,
                                                         int cssel, int cfsel) {
    __shared__ float hfl[NODE][258];     // 92,880 B  panel (HF, later HS)
    __shared__ float Pm[NODE][92];       // 33,120 B  At -> P
    __shared__ float t2s[NODE][34];      // 12,240 B  T2 32-col chunk
    __shared__ float rmax_[NODE], rinv_[NODE], fn_[NODE], gm_[NODE];

    int b = blockIdx.x;
    int tid = threadIdx.x;
    const float* HF = selbuf(hfsel) + (size_t)b * NODE * HID;
    const float* HS = selbuf(hssel) + (size_t)b * NODE * HID;
    const float* T2 = g_T + (size_t)b * NODE * HID;

    // stage HF panel (float4, coalesced)
    for (int i = tid; i < NODE * 64; i += CO_THREADS) {
        int n = i >> 6, c4 = (i & 63) << 2;
        *(float4*)&hfl[n][c4] = *(const float4*)&HF[(size_t)n * HID + c4];
    }

    // ---- phase 1: scores, 3 m-rows x 6 n-rows per thread ----
    {
        const int tm = tid & 31;
        const int tn5 = tid >> 5;          // 0..15
        const float* hr0 = hfl[tm];
        const float* hr1 = hfl[tm + 32];
        const float* hr2 = hfl[(tm < 26) ? tm + 64 : 0];
        const float* tr[6];
#pragma unroll
        for (int k = 0; k < 6; k++) {
            int n = tn5 + 16 * k;
            tr[k] = t2s[(n < NODE) ? n : 0];
        }
        float at[3][6];
#pragma unroll
        for (int i = 0; i < 3; i++)
#pragma unroll
            for (int k = 0; k < 6; k++) at[i][k] = 0.f;

        for (int d0 = 0; d0 < HID; d0 += 32) {
            __syncthreads();   // previous chunk fully consumed (also covers hfl staging)
            for (int i = tid; i < NODE * 32; i += CO_THREADS) {
                int n = i >> 5, dd = i & 31;
                t2s[n][dd] = T2[(size_t)n * HID + d0 + dd];
            }
            __syncthreads();
#pragma unroll
            for (int dd = 0; dd < 32; dd += 2) {
                float2 a0 = *(const float2*)&hr0[d0 + dd];
                float2 a1 = *(const float2*)&hr1[d0 + dd];
                float2 a2 = *(const float2*)&hr2[d0 + dd];
#pragma unroll
                for (int k = 0; k < 6; k++) {
                    float2 bk = *(const float2*)&tr[k][dd];
                    at[0][k] = fmaf(a0.x, bk.x, at[0][k]);
                    at[0][k] = fmaf(a0.y, bk.y, at[0][k]);
                    at[1][k] = fmaf(a1.x, bk.x, at[1][k]);
                    at[1][k] = fmaf(a1.y, bk.y, at[1][k]);
                    at[2][k] = fmaf(a2.x, bk.x, at[2][k]);
                    at[2][k] = fmaf(a2.y, bk.y, at[2][k]);
                }
            }
        }
        __syncthreads();
        int mv[3] = {tm, tm + 32, tm + 64};
#pragma unroll
        for (int i = 0; i < 3; i++) {
            if (mv[i] < NODE) {
#pragma unroll
                for (int k = 0; k < 6; k++) {
                    int n = tn5 + 16 * k;
                    if (n < NODE) Pm[n][mv[i]] = tanh_safe(at[i][k]);
                }
            }
        }
    }
    __syncthreads();

    // ---- softmax stats ----
    if (tid < NODE) {
        int n = tid;
        float mx = -2.f;
        for (int m = 0; m < NODE; m++) mx = fmaxf(mx, Pm[n][m]);
        float s = 0.f;
        for (int m = 0; m < NODE; m++) s += __expf(Pm[n][m] - mx);
        rmax_[n] = mx;
        rinv_[n] = 1.f / s;
        fn_[n] = s * __expf(mx);           // Σ_m exp(At[n][m])
    } else if (tid >= 256 && tid < 256 + NODE) {
        int m = tid - 256;
        float mx = -2.f;
        for (int n = 0; n < NODE; n++) mx = fmaxf(mx, Pm[n][m]);
        float s = 0.f;
        for (int n = 0; n < NODE; n++) s += __expf(Pm[n][m] - mx);
        gm_[m] = __expf(-mx) / s;          // 1 / Σ_n exp(At[n][m])
    }
    __syncthreads();

    // ---- P = row-softmax(At) in place ----
    for (int i = tid; i < NODE * NODE; i += CO_THREADS) {
        int n = i / NODE, m = i - n * NODE;
        Pm[n][m] = __expf(Pm[n][m] - rmax_[n]) * rinv_[n];
    }
    __syncthreads();

    // ---- phase 2: co_s = P @ HF ----
    {
        const int tc4 = (tid & 63) << 2;
        const int tnn = tid >> 6;          // 0..7
        int nrow[12];
#pragma unroll
        for (int k = 0; k < 12; k++) {
            int n = tnn + 8 * k;
            nrow[k] = (n < NODE) ? n : 0;
        }
        float acc[12][4];
#pragma unroll
        for (int k = 0; k < 12; k++)
#pragma unroll
            for (int j = 0; j < 4; j++) acc[k][j] = 0.f;

#pragma unroll 2
        for (int m = 0; m < NODE; m++) {
            float4 h = *(const float4*)&hfl[m][tc4];
#pragma unroll
            for (int k = 0; k < 12; k++) {
                float p = Pm[nrow[k]][m];
                acc[k][0] = fmaf(p, h.x, acc[k][0]);
                acc[k][1] = fmaf(p, h.y, acc[k][1]);
                acc[k][2] = fmaf(p, h.z, acc[k][2]);
                acc[k][3] = fmaf(p, h.w, acc[k][3]);
            }
        }
        float* cs = selbuf(cssel);
#pragma unroll
        for (int k = 0; k < 12; k++) {
            int n = tnn + 8 * k;
            if (n < NODE) {
                size_t row = (size_t)(b * NODE + n);
                float4 o = make_float4(acc[k][0], acc[k][1], acc[k][2], acc[k][3]);
                *(float4*)&outS[row * 512 + tc4] = o;
                *(float4*)&cs[row * HID + tc4] = o;
            }
        }
    }
    __syncthreads();

    // ---- reload panel with HS; P *= fn[n] ----
    for (int i = tid; i < NODE * 64; i += CO_THREADS) {
        int n = i >> 6, c4 = (i & 63) << 2;
        *(float4*)&hfl[n][c4] = *(const float4*)&HS[(size_t)n * HID + c4];
    }
    for (int i = tid; i < NODE * NODE; i += CO_THREADS) {
        int n = i / NODE, m = i - n * NODE;
        Pm[n][m] *= fn_[n];
    }
    __syncthreads();

    // ---- phase 3: co_f[m] = gm[m] * Σ_n P'[n][m] * HS[n] ----
    {
        const int tc4 = (tid & 63) << 2;
        const int tmm = tid >> 6;
        int mrow[12];
#pragma unroll
        for (int k = 0; k < 12; k++) {
            int m = tmm + 8 * k;
            mrow[k] = (m < NODE) ? m : 0;
        }
        float acc[12][4];
#pragma unroll
        for (int k = 0; k < 12; k++)
#pragma unroll
            for (int j = 0; j < 4; j++) acc[k][j] = 0.f;

#pragma unroll 2
        for (int n = 0; n < NODE; n++) {
            float4 h = *(const float4*)&hfl[n][tc4];
#pragma unroll
            for (int k = 0; k < 12; k++) {
                float p = Pm[n][mrow[k]];
                acc[k][0] = fmaf(p, h.x, acc[k][0]);
                acc[k][1] = fmaf(p, h.y, acc[k][1]);
                acc[k][2] = fmaf(p, h.z, acc[k][2]);
                acc[k][3] = fmaf(p, h.w, acc[k][3]);
            }
        }
        float* cf = selbuf(cfsel);
#pragma unroll
        for (int k = 0; k < 12; k++) {
            int m = tmm + 8 * k;
            if (m < NODE) {
                float g = gm_[m];
                size_t row = (size_t)(b * NODE + m);
                float4 o = make_float4(acc[k][0] * g, acc[k][1] * g,
                                       acc[k][2] * g, acc[k][3] * g);
                *(float4*)&outF[row * 512 + tc4] = o;
                *(float4*)&cf[row * HID + tc4] = o;
            }
        }
    }
}

// ---------------------------------------------------------------------------
extern "C" void kernel_launch(void* const* d_in, const int* in_sizes, int n_in,
                              void* d_out, int out_size, void* d_ws, size_t ws_size,
                              hipStream_t stream) {
    const float* x_sc = (const float*)d_in[0];
    const void* e_sc = d_in[1];
    const float* x_fc = (const float*)d_in[2];
    const void* e_fc = d_in[3];
    const float* W0 = (const float*)d_in[4];
    const float* b0 = (const float*)d_in[5];
    const float* W1 = (const float*)d_in[6];
    const float* b1 = (const float*)d_in[7];
    const float* Wa = (const float*)d_in[8];

    float* out = (float*)d_out;
    size_t os = (size_t)NN * 512;
    float* x1s = out;
    float* x2s = out + os;
    float* x1f = out + 2 * os;
    float* x2f = out + 3 * os;

    const int GEMM_GRID = (NN / BM) * 2;   // 720

    k_detect<<<1, 64, 0, stream>>>(e_sc);
    k_zero_adj<<<2048, 256, 0, stream>>>();
    k_build_adj<<<1024, 256, 0, stream>>>(e_sc, 0);
    k_build_adj<<<1024, 256, 0, stream>>>(e_fc, 1);
    k_norm_adj<<<NB, 128, 0, stream>>>(0);
    k_norm_adj<<<NB, 128, 0, stream>>>(1);

    // ---- layer 1 ----
    k_gemm_tile<<<GEMM_GRID, 256, 0, stream>>>(x_sc, -1, -1, NODE, NODE, W0);
    k_agg_tile<<<NB * 2, 256, 0, stream>>>(0, b0, /*hs*/0, x1s);
    k_gemm_tile<<<GEMM_GRID, 256, 0, stream>>>(x_fc, -1, -1, NODE, NODE, W0);
    k_agg_tile<<<NB * 2, 256, 0, stream>>>(1, b0, /*hf*/1, x1f);

    // ---- co-attention 1 ----
    k_gemm_tile<<<GEMM_GRID, 256, 0, stream>>>(nullptr, /*hs*/0, -1, HID, HID, Wa);
    k_coatt<<<NB, CO_THREADS, 0, stream>>>(/*hf*/1, /*hs*/0, x1s + HID, x1f + HID, 2, 3);

    // ---- layer 2 ----
    k_gemm_tile<<<GEMM_GRID, 256, 0, stream>>>(nullptr, /*hs*/0, /*cs*/2, 512, HID, W1);
    k_agg_tile<<<NB * 2, 256, 0, stream>>>(0, b1, /*hs2*/0, x2s);
    k_gemm_tile<<<GEMM_GRID, 256, 0, stream>>>(nullptr, /*hf*/1, /*cf*/3, 512, HID, W1);
    k_agg_tile<<<NB * 2, 256, 0, stream>>>(1, b1, /*hf2*/1, x2f);

    // ---- co-attention 2 ----
    k_gemm_tile<<<GEMM_GRID, 256, 0, stream>>>(nullptr, /*hs2*/0, -1, HID, HID, Wa);
    k_coatt<<<NB, CO_THREADS, 0, stream>>>(/*hf2*/1, /*hs2*/0, x2s + HID, x2f + HID, 2, 3);
}